// Round 1
// baseline (1324.335 us; speedup 1.0000x reference)
//
#include <hip/hip_runtime.h>
#include <hip/hip_bf16.h>

// Problem constants (static per reference):
//   protein_embeds: [N=2048, L=512, D=256] float32
//   batch_keys:     [N=2048] sorted ints in [0, 256), every segment non-empty
//   out:            [B=256, D=256] float32 = segment mean over all tokens
#define N_PROT 2048
#define L_SEQ  512
#define D_DIM  256
#define B_SEG  256
#define SPLIT  2           // blocks per protein along L
#define ROWS_PER_BLK (L_SEQ / SPLIT)   // 256

// Sum kernel: grid = N_PROT*SPLIT blocks, 256 threads.
// Thread layout: dq = tid & 63 (float4 lane across D=256), r = tid >> 6 (row group 0..3).
// Each wave (64 lanes) reads one contiguous 1 KiB row per iteration -> 16 B/lane coalesced.
__global__ __launch_bounds__(256) void seg_sum_kernel(const float* __restrict__ x,
                                                      const int* __restrict__ keys,
                                                      float* __restrict__ out) {
    const int blk  = blockIdx.x;
    const int prot = blk >> 1;          // / SPLIT
    const int part = blk & (SPLIT - 1); // % SPLIT
    const int tid  = threadIdx.x;
    const int dq   = tid & 63;
    const int r    = tid >> 6;

    const float4* row_base = (const float4*)(x + (size_t)(prot * L_SEQ + part * ROWS_PER_BLK) * D_DIM);
    // row stride in float4 units = D_DIM/4 = 64
    float4 acc = make_float4(0.f, 0.f, 0.f, 0.f);
    #pragma unroll 4
    for (int l = r; l < ROWS_PER_BLK; l += 4) {
        float4 v = row_base[(size_t)l * (D_DIM / 4) + dq];
        acc.x += v.x; acc.y += v.y; acc.z += v.z; acc.w += v.w;
    }

    // Reduce the 4 row-groups through LDS (4 KiB).
    __shared__ float4 lds[256];
    lds[tid] = acc;
    __syncthreads();
    if (r == 0) {
        float4 a = lds[dq];
        float4 b = lds[dq + 64];
        float4 c = lds[dq + 128];
        float4 d = lds[dq + 192];
        float sx = (a.x + b.x) + (c.x + d.x);
        float sy = (a.y + b.y) + (c.y + d.y);
        float sz = (a.z + b.z) + (c.z + d.z);
        float sw = (a.w + b.w) + (c.w + d.w);
        const int key = keys[prot];
        float* o = out + (size_t)key * D_DIM + dq * 4;
        atomicAdd(o + 0, sx);
        atomicAdd(o + 1, sy);
        atomicAdd(o + 2, sz);
        atomicAdd(o + 3, sw);
    }
}

// Finalize: grid = B_SEG blocks (one per segment), 256 threads (one per d).
// Count of proteins in segment b via binary search on sorted keys; divide in place.
__global__ __launch_bounds__(256) void finalize_kernel(const int* __restrict__ keys,
                                                       float* __restrict__ out) {
    const int b = blockIdx.x;
    const int d = threadIdx.x;

    // lower_bound(b)
    int lo = 0, hi = N_PROT;
    while (lo < hi) { int mid = (lo + hi) >> 1; if (keys[mid] <  b) lo = mid + 1; else hi = mid; }
    const int start = lo;
    // upper_bound(b)
    lo = start; hi = N_PROT;
    while (lo < hi) { int mid = (lo + hi) >> 1; if (keys[mid] <= b) lo = mid + 1; else hi = mid; }
    const int cnt_tokens = (lo - start) * L_SEQ;   // every segment non-empty per reference

    const float inv = 1.0f / (float)cnt_tokens;
    out[(size_t)b * D_DIM + d] *= inv;
}

extern "C" void kernel_launch(void* const* d_in, const int* in_sizes, int n_in,
                              void* d_out, int out_size, void* d_ws, size_t ws_size,
                              hipStream_t stream) {
    const float* x    = (const float*)d_in[0];
    const int*   keys = (const int*)d_in[1];
    float* out        = (float*)d_out;

    // d_out is poisoned with 0xAA before every timed launch -> zero it (atomic accumulate target).
    hipMemsetAsync(out, 0, (size_t)out_size * sizeof(float), stream);

    seg_sum_kernel<<<N_PROT * SPLIT, 256, 0, stream>>>(x, keys, out);
    finalize_kernel<<<B_SEG, 256, 0, stream>>>(keys, out);
}